// Round 2
// baseline (147.565 us; speedup 1.0000x reference)
//
#include <hip/hip_runtime.h>

// NGF loss: g = normalized gradient (central diff interior, one-sided at edges),
// loss = 1 - mean( (g0 . g1)^2 ).  B=64, C=1, H=512, W=512, fp32.
//
// R11 = R10 resubmitted verbatim (R10's bench died on container acquisition,
// not on the kernel — no counters returned, hypothesis untested).
// R10 theory: kernel delivers 3.3 TB/s read = ~80 outstanding 64B lines/CU at
// 900cy HBM latency. Prior "occupancy" trials varied launch_bounds on a
// 2048-wave grid -> resident waves/CU was pinned at 8 (2/SIMD) regardless.
// This version doubles the GRID to 4096 waves (RPT=8) with VGPRs capped at 128
// (__launch_bounds__(256,4)) so 16 waves/CU are co-resident in one round.
// If the outstanding-request limit is per-wave (vmcnt serialization), read BW
// ~doubles; if it's a per-CU MSHR pool, this is neutral and we're at roofline.
// NT loads dropped (R8 vs R9 proved them neutral; nt hurts halo L2 retention,
// and adjacent chunks now share halo rows within a block = same CU).

#define HH 512
#define WW 512
#define NGF_EPS 1e-10f
#define RPT 8    // rows walked per wave

typedef float vf4 __attribute__((ext_vector_type(4)));

__device__ __forceinline__ float rcp_fast(float x) { return __builtin_amdgcn_rcpf(x); }
__device__ __forceinline__ vf4 ld4(const float* p) { return *(const vf4*)p; }

// waves = 64 imgs * (512/RPT = 64 chunks) = 4096 -> 1024 blocks x 256 threads
// launch_bounds(256,4): 4 waves/EU -> 4 blocks/CU -> 16 waves/CU resident.
__global__ __launch_bounds__(256, 4) void ngf_partial(const float* __restrict__ I0,
                                                      const float* __restrict__ I1,
                                                      float* __restrict__ partials) {
    const int tid  = threadIdx.x;
    const int wv   = tid >> 6;
    const int lane = tid & 63;
    const int gw   = blockIdx.x * 4 + wv;   // global wave id, 0..4095
    const int img  = gw >> 6;               // 0..63
    const int ck   = gw & 63;               // row-chunk 0..63
    const int h0   = ck * RPT;

    const float* p0 = I0 + (size_t)img * (HH * WW) + lane * 8;
    const float* p1 = I1 + (size_t)img * (HH * WW) + lane * 8;

    // 3-row window (u = h-1 clamped, c = h, n = h+1) + prefetch m = h+2.
    vf4 u0a, u0b, u1a, u1b, c0a, c0b, c1a, c1b, n0a, n0b, n1a, n1b;
    {
        const int ru = (h0 > 0) ? (h0 - 1) * WW : 0;
        const int rc = h0 * WW;
        const int rn = (h0 + 1) * WW;       // h0 <= 504 -> always valid
        u0a = ld4(p0 + ru);     u0b = ld4(p0 + ru + 4);
        u1a = ld4(p1 + ru);     u1b = ld4(p1 + ru + 4);
        c0a = ld4(p0 + rc);     c0b = ld4(p0 + rc + 4);
        c1a = ld4(p1 + rc);     c1b = ld4(p1 + rc + 4);
        n0a = ld4(p0 + rn);     n0b = ld4(p0 + rn + 4);
        n1a = ld4(p1 + rn);     n1b = ld4(p1 + rn + 4);
    }

    float s = 0.f;
#pragma unroll
    for (int i = 0; i < RPT; ++i) {
        const int h  = h0 + i;
        const int hm = (h + 2 < HH) ? h + 2 : HH - 1;     // prefetch row, clamped
        const int rm = hm * WW;
        const vf4 m0a = ld4(p0 + rm);
        const vf4 m0b = ld4(p0 + rm + 4);
        const vf4 m1a = ld4(p1 + rm);
        const vf4 m1b = ld4(p1 + rm + 4);

        // W-halos from neighbors' center-row registers; image edges clamp.
        float L0 = __shfl_up(c0b.w, 1, 64);   if (lane == 0)  L0 = c0a.x;
        float R0 = __shfl_down(c0a.x, 1, 64); if (lane == 63) R0 = c0b.w;
        float L1 = __shfl_up(c1b.w, 1, 64);   if (lane == 0)  L1 = c1a.x;
        float R1 = __shfl_down(c1a.x, 1, 64); if (lane == 63) R1 = c1b.w;

        const float a0[10] = {L0, c0a.x, c0a.y, c0a.z, c0a.w,
                                  c0b.x, c0b.y, c0b.z, c0b.w, R0};
        const float a1[10] = {L1, c1a.x, c1a.y, c1a.z, c1a.w,
                                  c1b.x, c1b.y, c1b.z, c1b.w, R1};
        const float gx0[8] = {n0a.x - u0a.x, n0a.y - u0a.y, n0a.z - u0a.z, n0a.w - u0a.w,
                              n0b.x - u0b.x, n0b.y - u0b.y, n0b.z - u0b.z, n0b.w - u0b.w};
        const float gx1[8] = {n1a.x - u1a.x, n1a.y - u1a.y, n1a.z - u1a.z, n1a.w - u1a.w,
                              n1b.x - u1b.x, n1b.y - u1b.y, n1b.z - u1b.z, n1b.w - u1b.w};
#pragma unroll
        for (int j = 0; j < 8; ++j) {
            const float gy0 = a0[j + 2] - a0[j];
            const float gy1 = a1[j + 2] - a1[j];
            const float q0  = gx0[j] * gx0[j] + gy0 * gy0 + NGF_EPS;
            const float q1  = gx1[j] * gx1[j] + gy1 * gy1 + NGF_EPS;
            const float cr  = gx0[j] * gx1[j] + gy0 * gy1;
            s += cr * cr * rcp_fast(q0 * q1);   // dot^2 = cross^2/(n0*n1)
        }
        // rotate window (pure register renaming under full unroll)
        u0a = c0a; u0b = c0b; u1a = c1a; u1b = c1b;
        c0a = n0a; c0b = n0b; c1a = n1a; c1b = n1b;
        n0a = m0a; n0b = m0b; n1a = m1a; n1b = m1b;
    }

    // wave64 reduce; lane 0 writes this wave's partial directly (no LDS).
#pragma unroll
    for (int off = 32; off > 0; off >>= 1) s += __shfl_down(s, off, 64);
    if (lane == 0) partials[gw] = s;
}

// 4096 partials: 1024 threads x vf4, one block.
__global__ __launch_bounds__(1024) void ngf_finalize(const float* __restrict__ partials,
                                                     float inv_n,
                                                     float* __restrict__ out) {
    const vf4 v = *(const vf4*)(partials + threadIdx.x * 4);
    float s = v.x + v.y + v.z + v.w;
#pragma unroll
    for (int off = 32; off > 0; off >>= 1) s += __shfl_down(s, off, 64);

    __shared__ float lds[16];
    const int wave = threadIdx.x >> 6;
    const int lane = threadIdx.x & 63;
    if (lane == 0) lds[wave] = s;
    __syncthreads();
    if (threadIdx.x == 0) {
        float tot = 0.f;
#pragma unroll
        for (int i = 0; i < 16; ++i) tot += lds[i];
        out[0] = 1.0f - tot * inv_n;
    }
}

extern "C" void kernel_launch(void* const* d_in, const int* in_sizes, int n_in,
                              void* d_out, int out_size, void* d_ws, size_t ws_size,
                              hipStream_t stream) {
    const float* I0 = (const float*)d_in[0];
    const float* I1 = (const float*)d_in[1];
    float* partials = (float*)d_ws;          // 4096 floats = 16 KB

    const int N = in_sizes[0];               // 16,777,216
    ngf_partial<<<1024, 256, 0, stream>>>(I0, I1, partials);
    ngf_finalize<<<1, 1024, 0, stream>>>(partials, 1.0f / (float)N, (float*)d_out);
}

// Round 3
// 146.625 us; speedup vs baseline: 1.0064x; 1.0064x over previous
//
#include <hip/hip_runtime.h>

// NGF loss: g = normalized gradient (central diff interior, one-sided at edges),
// loss = 1 - mean( (g0 . g1)^2 ).  B=64, C=1, H=512, W=512, fp32.
//
// R12: R11 falsified the per-wave-vmcnt theory (16 waves/CU was SLOWER: 47us vs
// <40.3us at 8 waves/CU). Limit is a per-CU outstanding-line pool (~64 lines):
// any wave keeps >=4 load instrs (64 lines) in flight, so 4 waves/CU saturate it.
// Counters: FETCH 82MB < 128MB unique (L3 serves 1/3), hbm 1.75 TB/s, VALU 14%
// -> latency*line-pool bound, not HBM/compute. Only lever left: fewer L1-miss
// lines per useful byte.
//   1) RPT 8->32: halo amplification 1.25x -> 1.0625x (136MB logical).
//   2) Snake walk (odd chunks bottom-up): shared boundary rows of adjacent
//      chunks are touched temporally together on the same CU (end-end or
//      start-start) -> second toucher hits L1/L2, no full-latency line slot.
//      Single code path: signed row stride dir; gx negates for BOTH images and
//      the loss uses only gx^2 / gx0*gx1, so the sign cancels exactly.

#define HH 512
#define WW 512
#define NGF_EPS 1e-10f
#define RPT 32   // rows walked per wave; 16 chunks per image

typedef float vf4 __attribute__((ext_vector_type(4)));

__device__ __forceinline__ float rcp_fast(float x) { return __builtin_amdgcn_rcpf(x); }
__device__ __forceinline__ vf4 ld4(const float* p) { return *(const vf4*)p; }
__device__ __forceinline__ int clampr(int h) { return h < 0 ? 0 : (h > HH - 1 ? HH - 1 : h); }

// waves = 64 imgs * 16 chunks = 1024 -> 256 blocks x 256 threads (1 block/CU).
__global__ __launch_bounds__(256) void ngf_partial(const float* __restrict__ I0,
                                                   const float* __restrict__ I1,
                                                   float* __restrict__ partials) {
    const int tid  = threadIdx.x;
    const int wv   = tid >> 6;
    const int lane = tid & 63;
    const int gw   = blockIdx.x * 4 + wv;   // global wave id, 0..1023
    const int img  = gw >> 4;               // 0..63
    const int ck   = gw & 15;               // row-chunk 0..15
    const int rev  = ck & 1;                // snake: odd chunks walk bottom-up
    const int dir  = rev ? -1 : 1;
    const int hstart = ck * RPT + (rev ? RPT - 1 : 0);

    const float* p0 = I0 + (size_t)img * (HH * WW) + lane * 8;
    const float* p1 = I1 + (size_t)img * (HH * WW) + lane * 8;

    // 3-row window in walk order: u = row(h-dir), c = row(h), n = row(h+dir),
    // all clamped to the image. Prefetch m = row(h+2*dir).
    vf4 u0a, u0b, u1a, u1b, c0a, c0b, c1a, c1b, n0a, n0b, n1a, n1b;
    {
        const int ru = clampr(hstart - dir) * WW;
        const int rc = hstart * WW;
        const int rn = clampr(hstart + dir) * WW;
        u0a = ld4(p0 + ru);     u0b = ld4(p0 + ru + 4);
        u1a = ld4(p1 + ru);     u1b = ld4(p1 + ru + 4);
        c0a = ld4(p0 + rc);     c0b = ld4(p0 + rc + 4);
        c1a = ld4(p1 + rc);     c1b = ld4(p1 + rc + 4);
        n0a = ld4(p0 + rn);     n0b = ld4(p0 + rn + 4);
        n1a = ld4(p1 + rn);     n1b = ld4(p1 + rn + 4);
    }

    float s = 0.f;
#pragma unroll
    for (int i = 0; i < RPT; ++i) {
        const int h  = hstart + dir * i;
        const int rm = clampr(h + 2 * dir) * WW;          // prefetch row, clamped
        const vf4 m0a = ld4(p0 + rm);
        const vf4 m0b = ld4(p0 + rm + 4);
        const vf4 m1a = ld4(p1 + rm);
        const vf4 m1b = ld4(p1 + rm + 4);

        // W-halos from neighbors' center-row registers; image edges clamp.
        float L0 = __shfl_up(c0b.w, 1, 64);   if (lane == 0)  L0 = c0a.x;
        float R0 = __shfl_down(c0a.x, 1, 64); if (lane == 63) R0 = c0b.w;
        float L1 = __shfl_up(c1b.w, 1, 64);   if (lane == 0)  L1 = c1a.x;
        float R1 = __shfl_down(c1a.x, 1, 64); if (lane == 63) R1 = c1b.w;

        const float a0[10] = {L0, c0a.x, c0a.y, c0a.z, c0a.w,
                                  c0b.x, c0b.y, c0b.z, c0b.w, R0};
        const float a1[10] = {L1, c1a.x, c1a.y, c1a.z, c1a.w,
                                  c1b.x, c1b.y, c1b.z, c1b.w, R1};
        // gx = n - u = dir * (true vertical gradient); dir cancels in the loss.
        const float gx0[8] = {n0a.x - u0a.x, n0a.y - u0a.y, n0a.z - u0a.z, n0a.w - u0a.w,
                              n0b.x - u0b.x, n0b.y - u0b.y, n0b.z - u0b.z, n0b.w - u0b.w};
        const float gx1[8] = {n1a.x - u1a.x, n1a.y - u1a.y, n1a.z - u1a.z, n1a.w - u1a.w,
                              n1b.x - u1b.x, n1b.y - u1b.y, n1b.z - u1b.z, n1b.w - u1b.w};
#pragma unroll
        for (int j = 0; j < 8; ++j) {
            const float gy0 = a0[j + 2] - a0[j];
            const float gy1 = a1[j + 2] - a1[j];
            const float q0  = gx0[j] * gx0[j] + gy0 * gy0 + NGF_EPS;
            const float q1  = gx1[j] * gx1[j] + gy1 * gy1 + NGF_EPS;
            const float cr  = gx0[j] * gx1[j] + gy0 * gy1;
            s += cr * cr * rcp_fast(q0 * q1);   // dot^2 = cross^2/(n0*n1)
        }
        // rotate window toward h+dir (pure register renaming under full unroll):
        // u' = row(h) = c, c' = row(h+dir) = n, n' = row(h+2dir) = m.
        u0a = c0a; u0b = c0b; u1a = c1a; u1b = c1b;
        c0a = n0a; c0b = n0b; c1a = n1a; c1b = n1b;
        n0a = m0a; n0b = m0b; n1a = m1a; n1b = m1b;
    }

    // wave64 reduce; lane 0 writes this wave's partial directly (no LDS).
#pragma unroll
    for (int off = 32; off > 0; off >>= 1) s += __shfl_down(s, off, 64);
    if (lane == 0) partials[gw] = s;
}

// 1024 partials: 256 threads x vf4, one block.
__global__ __launch_bounds__(256) void ngf_finalize(const float* __restrict__ partials,
                                                    float inv_n,
                                                    float* __restrict__ out) {
    const vf4 v = *(const vf4*)(partials + threadIdx.x * 4);
    float s = v.x + v.y + v.z + v.w;
#pragma unroll
    for (int off = 32; off > 0; off >>= 1) s += __shfl_down(s, off, 64);

    __shared__ float lds[4];
    const int wave = threadIdx.x >> 6;
    const int lane = threadIdx.x & 63;
    if (lane == 0) lds[wave] = s;
    __syncthreads();
    if (threadIdx.x == 0) {
        float tot = 0.f;
#pragma unroll
        for (int i = 0; i < 4; ++i) tot += lds[i];
        out[0] = 1.0f - tot * inv_n;
    }
}

extern "C" void kernel_launch(void* const* d_in, const int* in_sizes, int n_in,
                              void* d_out, int out_size, void* d_ws, size_t ws_size,
                              hipStream_t stream) {
    const float* I0 = (const float*)d_in[0];
    const float* I1 = (const float*)d_in[1];
    float* partials = (float*)d_ws;          // 1024 floats = 4 KB

    const int N = in_sizes[0];               // 16,777,216
    ngf_partial<<<256, 256, 0, stream>>>(I0, I1, partials);
    ngf_finalize<<<1, 256, 0, stream>>>(partials, 1.0f / (float)N, (float*)d_out);
}

// Round 4
// 144.393 us; speedup vs baseline: 1.0220x; 1.0155x over previous
//
#include <hip/hip_runtime.h>

// NGF loss: g = normalized gradient (central diff interior, one-sided at edges),
// loss = 1 - mean( (g0 . g1)^2 ).  B=64, C=1, H=512, W=512, fp32.
//
// R13: model settled by R11/R12: time ~ full-latency miss lines / per-CU miss
// pool; pool saturates at >=8 waves/CU (8 and 16 both ~3.5 TB/s miss-BW, 4
// gives 2.8). R0 (RPT=16, 8 waves/CU, 1.125x halo) = 40us; floor = 128MB
// unique / 3.6 TB/s = 35.5us. This round: R0's geometry (RPT=16, 2048 waves,
// 512x256, 8 waves/CU) + R12's verified snake walk (odd chunks bottom-up).
// Snake pairs boundary-row touches temporally (end-end / start-start) within
// a block (same CU) so ~3/4 of halo re-reads become L1/L2 hits: effective
// misses 1.125x -> ~1.02x (~131MB). Plain loads (no NT) so L1 can serve the
// second toucher. gx sign flips with walk direction for BOTH images; loss uses
// only gx^2 and gx0*gx1 so the sign cancels exactly (verified in R12).

#define HH 512
#define WW 512
#define NGF_EPS 1e-10f
#define RPT 16   // rows walked per wave; 32 chunks per image

typedef float vf4 __attribute__((ext_vector_type(4)));

__device__ __forceinline__ float rcp_fast(float x) { return __builtin_amdgcn_rcpf(x); }
__device__ __forceinline__ vf4 ld4(const float* p) { return *(const vf4*)p; }
__device__ __forceinline__ int clampr(int h) { return h < 0 ? 0 : (h > HH - 1 ? HH - 1 : h); }

// waves = 64 imgs * 32 chunks = 2048 -> 512 blocks x 256 threads (8 waves/CU).
__global__ __launch_bounds__(256) void ngf_partial(const float* __restrict__ I0,
                                                   const float* __restrict__ I1,
                                                   float* __restrict__ partials) {
    const int tid  = threadIdx.x;
    const int wv   = tid >> 6;
    const int lane = tid & 63;
    const int gw   = blockIdx.x * 4 + wv;   // global wave id, 0..2047
    const int img  = gw >> 5;               // 0..63
    const int ck   = gw & 31;               // row-chunk 0..31 (4 consecutive per block)
    const int rev  = ck & 1;                // snake: odd chunks walk bottom-up
    const int dir  = rev ? -1 : 1;
    const int hstart = ck * RPT + (rev ? RPT - 1 : 0);

    const float* p0 = I0 + (size_t)img * (HH * WW) + lane * 8;
    const float* p1 = I1 + (size_t)img * (HH * WW) + lane * 8;

    // 3-row window in walk order: u = row(h-dir), c = row(h), n = row(h+dir),
    // all clamped to the image. Prefetch m = row(h+2*dir).
    vf4 u0a, u0b, u1a, u1b, c0a, c0b, c1a, c1b, n0a, n0b, n1a, n1b;
    {
        const int ru = clampr(hstart - dir) * WW;
        const int rc = hstart * WW;
        const int rn = clampr(hstart + dir) * WW;
        u0a = ld4(p0 + ru);     u0b = ld4(p0 + ru + 4);
        u1a = ld4(p1 + ru);     u1b = ld4(p1 + ru + 4);
        c0a = ld4(p0 + rc);     c0b = ld4(p0 + rc + 4);
        c1a = ld4(p1 + rc);     c1b = ld4(p1 + rc + 4);
        n0a = ld4(p0 + rn);     n0b = ld4(p0 + rn + 4);
        n1a = ld4(p1 + rn);     n1b = ld4(p1 + rn + 4);
    }

    float s = 0.f;
#pragma unroll
    for (int i = 0; i < RPT; ++i) {
        const int h  = hstart + dir * i;
        const int rm = clampr(h + 2 * dir) * WW;          // prefetch row, clamped
        const vf4 m0a = ld4(p0 + rm);
        const vf4 m0b = ld4(p0 + rm + 4);
        const vf4 m1a = ld4(p1 + rm);
        const vf4 m1b = ld4(p1 + rm + 4);

        // W-halos from neighbors' center-row registers; image edges clamp.
        float L0 = __shfl_up(c0b.w, 1, 64);   if (lane == 0)  L0 = c0a.x;
        float R0 = __shfl_down(c0a.x, 1, 64); if (lane == 63) R0 = c0b.w;
        float L1 = __shfl_up(c1b.w, 1, 64);   if (lane == 0)  L1 = c1a.x;
        float R1 = __shfl_down(c1a.x, 1, 64); if (lane == 63) R1 = c1b.w;

        const float a0[10] = {L0, c0a.x, c0a.y, c0a.z, c0a.w,
                                  c0b.x, c0b.y, c0b.z, c0b.w, R0};
        const float a1[10] = {L1, c1a.x, c1a.y, c1a.z, c1a.w,
                                  c1b.x, c1b.y, c1b.z, c1b.w, R1};
        // gx = n - u = dir * (true vertical gradient); dir cancels in the loss.
        const float gx0[8] = {n0a.x - u0a.x, n0a.y - u0a.y, n0a.z - u0a.z, n0a.w - u0a.w,
                              n0b.x - u0b.x, n0b.y - u0b.y, n0b.z - u0b.z, n0b.w - u0b.w};
        const float gx1[8] = {n1a.x - u1a.x, n1a.y - u1a.y, n1a.z - u1a.z, n1a.w - u1a.w,
                              n1b.x - u1b.x, n1b.y - u1b.y, n1b.z - u1b.z, n1b.w - u1b.w};
#pragma unroll
        for (int j = 0; j < 8; ++j) {
            const float gy0 = a0[j + 2] - a0[j];
            const float gy1 = a1[j + 2] - a1[j];
            const float q0  = gx0[j] * gx0[j] + gy0 * gy0 + NGF_EPS;
            const float q1  = gx1[j] * gx1[j] + gy1 * gy1 + NGF_EPS;
            const float cr  = gx0[j] * gx1[j] + gy0 * gy1;
            s += cr * cr * rcp_fast(q0 * q1);   // dot^2 = cross^2/(n0*n1)
        }
        // rotate window toward h+dir (pure register renaming under full unroll):
        // u' = row(h) = c, c' = row(h+dir) = n, n' = row(h+2dir) = m.
        u0a = c0a; u0b = c0b; u1a = c1a; u1b = c1b;
        c0a = n0a; c0b = n0b; c1a = n1a; c1b = n1b;
        n0a = m0a; n0b = m0b; n1a = m1a; n1b = m1b;
    }

    // wave64 reduce; lane 0 writes this wave's partial directly (no LDS).
#pragma unroll
    for (int off = 32; off > 0; off >>= 1) s += __shfl_down(s, off, 64);
    if (lane == 0) partials[gw] = s;
}

// 2048 partials: 512 threads x vf4, one block.
__global__ __launch_bounds__(512) void ngf_finalize(const float* __restrict__ partials,
                                                    float inv_n,
                                                    float* __restrict__ out) {
    const vf4 v = *(const vf4*)(partials + threadIdx.x * 4);
    float s = v.x + v.y + v.z + v.w;
#pragma unroll
    for (int off = 32; off > 0; off >>= 1) s += __shfl_down(s, off, 64);

    __shared__ float lds[8];
    const int wave = threadIdx.x >> 6;
    const int lane = threadIdx.x & 63;
    if (lane == 0) lds[wave] = s;
    __syncthreads();
    if (threadIdx.x == 0) {
        float tot = 0.f;
#pragma unroll
        for (int i = 0; i < 8; ++i) tot += lds[i];
        out[0] = 1.0f - tot * inv_n;
    }
}

extern "C" void kernel_launch(void* const* d_in, const int* in_sizes, int n_in,
                              void* d_out, int out_size, void* d_ws, size_t ws_size,
                              hipStream_t stream) {
    const float* I0 = (const float*)d_in[0];
    const float* I1 = (const float*)d_in[1];
    float* partials = (float*)d_ws;          // 2048 floats = 8 KB

    const int N = in_sizes[0];               // 16,777,216
    ngf_partial<<<512, 256, 0, stream>>>(I0, I1, partials);
    ngf_finalize<<<1, 512, 0, stream>>>(partials, 1.0f / (float)N, (float*)d_out);
}

// Round 5
// 140.932 us; speedup vs baseline: 1.0471x; 1.0246x over previous
//
#include <hip/hip_runtime.h>

// NGF loss: g = normalized gradient (central diff interior, one-sided at edges),
// loss = 1 - mean( (g0 . g1)^2 ).  B=64, C=1, H=512, W=512, fp32.
//
// R14 = champion restore (R9/R0 verbatim). R11-R13 post-mortem: time is
// decoupled from HBM bytes (FETCH 67-134MB all land 40-52us); the binding
// variable is load flavor — every plain-load variant = 45-52us, NT = ~40us.
// Model: L1-allocate serializes the miss stream; nontemporal bypasses it, and
// underneath sits the ~3.3-3.5 TB/s per-CU request-pipeline ceiling that ten
// structures (7 prior + R11/R12/R13) all pin at. Byte-side optimization
// (snake/L3 residency) is counterproductive: it needs L1 retention, which
// costs more in allocate serialization than the bytes save (R13: -50% FETCH,
// +12% time). Kernel floor = 144MB / ~3.6 TB/s ~= 40us = where this sits.

#define HH 512
#define WW 512
#define NGF_EPS 1e-10f
#define RPT 16   // rows walked per wave

typedef float vf4 __attribute__((ext_vector_type(4)));

__device__ __forceinline__ float rcp_fast(float x) { return __builtin_amdgcn_rcpf(x); }
__device__ __forceinline__ vf4 ldnt(const float* p) {
    return __builtin_nontemporal_load((const vf4*)p);
}

// waves = 64 imgs * (512/RPT = 32 chunks) = 2048 -> 512 blocks x 256 threads
__global__ __launch_bounds__(256) void ngf_partial(const float* __restrict__ I0,
                                                   const float* __restrict__ I1,
                                                   float* __restrict__ partials) {
    const int tid  = threadIdx.x;
    const int wv   = tid >> 6;
    const int lane = tid & 63;
    const int gw   = blockIdx.x * 4 + wv;   // global wave id, 0..2047
    const int img  = gw >> 5;               // 0..63
    const int ck   = gw & 31;               // row-chunk 0..31
    const int h0   = ck * RPT;

    const float* p0 = I0 + (size_t)img * (HH * WW) + lane * 8;
    const float* p1 = I1 + (size_t)img * (HH * WW) + lane * 8;

    // 3-row window (u = h-1 clamped, c = h, n = h+1) + prefetch m = h+2.
    vf4 u0a, u0b, u1a, u1b, c0a, c0b, c1a, c1b, n0a, n0b, n1a, n1b;
    {
        const int ru = (h0 > 0) ? (h0 - 1) * WW : 0;
        const int rc = h0 * WW;
        const int rn = (h0 + 1) * WW;       // h0 <= 496 -> always valid
        u0a = ldnt(p0 + ru);     u0b = ldnt(p0 + ru + 4);
        u1a = ldnt(p1 + ru);     u1b = ldnt(p1 + ru + 4);
        c0a = ldnt(p0 + rc);     c0b = ldnt(p0 + rc + 4);
        c1a = ldnt(p1 + rc);     c1b = ldnt(p1 + rc + 4);
        n0a = ldnt(p0 + rn);     n0b = ldnt(p0 + rn + 4);
        n1a = ldnt(p1 + rn);     n1b = ldnt(p1 + rn + 4);
    }

    float s = 0.f;
#pragma unroll
    for (int i = 0; i < RPT; ++i) {
        const int h  = h0 + i;
        const int hm = (h + 2 < HH) ? h + 2 : HH - 1;     // prefetch row, clamped
        const int rm = hm * WW;
        const vf4 m0a = ldnt(p0 + rm);
        const vf4 m0b = ldnt(p0 + rm + 4);
        const vf4 m1a = ldnt(p1 + rm);
        const vf4 m1b = ldnt(p1 + rm + 4);

        // W-halos from neighbors' center-row registers; image edges clamp.
        float L0 = __shfl_up(c0b.w, 1, 64);   if (lane == 0)  L0 = c0a.x;
        float R0 = __shfl_down(c0a.x, 1, 64); if (lane == 63) R0 = c0b.w;
        float L1 = __shfl_up(c1b.w, 1, 64);   if (lane == 0)  L1 = c1a.x;
        float R1 = __shfl_down(c1a.x, 1, 64); if (lane == 63) R1 = c1b.w;

        const float a0[10] = {L0, c0a.x, c0a.y, c0a.z, c0a.w,
                                  c0b.x, c0b.y, c0b.z, c0b.w, R0};
        const float a1[10] = {L1, c1a.x, c1a.y, c1a.z, c1a.w,
                                  c1b.x, c1b.y, c1b.z, c1b.w, R1};
        const float gx0[8] = {n0a.x - u0a.x, n0a.y - u0a.y, n0a.z - u0a.z, n0a.w - u0a.w,
                              n0b.x - u0b.x, n0b.y - u0b.y, n0b.z - u0b.z, n0b.w - u0b.w};
        const float gx1[8] = {n1a.x - u1a.x, n1a.y - u1a.y, n1a.z - u1a.z, n1a.w - u1a.w,
                              n1b.x - u1b.x, n1b.y - u1b.y, n1b.z - u1b.z, n1b.w - u1b.w};
#pragma unroll
        for (int j = 0; j < 8; ++j) {
            const float gy0 = a0[j + 2] - a0[j];
            const float gy1 = a1[j + 2] - a1[j];
            const float q0  = gx0[j] * gx0[j] + gy0 * gy0 + NGF_EPS;
            const float q1  = gx1[j] * gx1[j] + gy1 * gy1 + NGF_EPS;
            const float cr  = gx0[j] * gx1[j] + gy0 * gy1;
            s += cr * cr * rcp_fast(q0 * q1);   // dot^2 = cross^2/(n0*n1)
        }
        // rotate window (pure register renaming under full unroll)
        u0a = c0a; u0b = c0b; u1a = c1a; u1b = c1b;
        c0a = n0a; c0b = n0b; c1a = n1a; c1b = n1b;
        n0a = m0a; n0b = m0b; n1a = m1a; n1b = m1b;
    }

    // wave64 reduce; lane 0 writes this wave's partial directly (no LDS).
#pragma unroll
    for (int off = 32; off > 0; off >>= 1) s += __shfl_down(s, off, 64);
    if (lane == 0) partials[gw] = s;
}

// 2048 partials: 512 threads x vf4, one block.
__global__ __launch_bounds__(512) void ngf_finalize(const float* __restrict__ partials,
                                                    float inv_n,
                                                    float* __restrict__ out) {
    const vf4 v = *(const vf4*)(partials + threadIdx.x * 4);
    float s = v.x + v.y + v.z + v.w;
#pragma unroll
    for (int off = 32; off > 0; off >>= 1) s += __shfl_down(s, off, 64);

    __shared__ float lds[8];
    const int wave = threadIdx.x >> 6;
    const int lane = threadIdx.x & 63;
    if (lane == 0) lds[wave] = s;
    __syncthreads();
    if (threadIdx.x == 0) {
        float tot = 0.f;
#pragma unroll
        for (int i = 0; i < 8; ++i) tot += lds[i];
        out[0] = 1.0f - tot * inv_n;
    }
}

extern "C" void kernel_launch(void* const* d_in, const int* in_sizes, int n_in,
                              void* d_out, int out_size, void* d_ws, size_t ws_size,
                              hipStream_t stream) {
    const float* I0 = (const float*)d_in[0];
    const float* I1 = (const float*)d_in[1];
    float* partials = (float*)d_ws;          // 2048 floats = 8 KB

    const int N = in_sizes[0];               // 16,777,216
    ngf_partial<<<512, 256, 0, stream>>>(I0, I1, partials);
    ngf_finalize<<<1, 512, 0, stream>>>(partials, 1.0f / (float)N, (float*)d_out);
}